// Round 2
// 933.766 us; speedup vs baseline: 1.0718x; 1.0718x over previous
//
#include <hip/hip_runtime.h>
#include <hip/hip_bf16.h>

typedef __attribute__((ext_vector_type(8))) short short8;
typedef __attribute__((ext_vector_type(4))) float floatx4;
typedef unsigned short ushort_t;

#define MFMA(a, b, c) __builtin_amdgcn_mfma_f32_16x16x32_bf16((a), (b), (c), 0, 0, 0)

constexpr int N_NODES = 50000;
constexpr int N_EDGES = 800000;
constexpr int EDGE_BLOCKS = N_EDGES / 32;        // 25000 (exact)
constexpr int NODE_TILES = (N_NODES + 63) / 64;  // 782
constexpr int YS_STRIDE = 136;                   // u16; 272B row, 16B-aligned, ~2-way bank alias (free)
constexpr int MS_STRIDE = 132;                   // f32; 528B row -> quad rows land on shifted banks

__device__ __forceinline__ unsigned short f2b(float x) {
  union { float f; unsigned u; } c; c.f = x;
  unsigned r = c.u + 0x7FFFu + ((c.u >> 16) & 1u);
  return (unsigned short)(r >> 16);
}

__device__ __forceinline__ unsigned pk2(float x, float y) {
  // packed RNE fp32->bf16 (v_cvt_pk_bf16_f32 on gfx950)
  __hip_bfloat162 h = __float22bfloat162_rn(float2{x, y});
  unsigned u; __builtin_memcpy(&u, &h, 4);
  return u;
}

__device__ __forceinline__ short8 mk_frag(const float4 a, const float4 b) {
  union { short8 s; unsigned u[4]; } r;
  r.u[0] = pk2(a.x, a.y); r.u[1] = pk2(a.z, a.w);
  r.u[2] = pk2(b.x, b.y); r.u[3] = pk2(b.z, b.w);
  return r.s;
}

// ---- prep: zero agg + zero dst-histogram + build weights ----
__global__ void prep(const float* __restrict__ W1a, const float* __restrict__ W1b,
                     const float* __restrict__ W2a, const float* __restrict__ W2b,
                     ushort_t* __restrict__ wbuf, float4* __restrict__ agg4,
                     unsigned* __restrict__ cnt) {
  const int t = blockIdx.x * blockDim.x + threadIdx.x;
  const int stride = gridDim.x * blockDim.x;
  const float4 z = {0.f, 0.f, 0.f, 0.f};
  for (int i = t; i < N_NODES * 32; i += stride) agg4[i] = z;
  for (int i = t; i < N_NODES; i += stride) cnt[i] = 0u;

  ushort_t* W1s1 = wbuf;           // 32768: GEMM1 frags (ks=0..7, nt=0..7)
  ushort_t* W1s2 = wbuf + 32768;   // 16384: GEMM2 frags (ks=0..3, nt=0..7)
  ushort_t* W2aT = wbuf + 49152;   // 16384
  ushort_t* W2bT = wbuf + 65536;   // 16384

  for (int i = t; i < 32768; i += stride) {
    const int j = i & 7, lane = (i >> 3) & 63, fb = i >> 9;
    const int ks = fb >> 3, nt = fb & 7;
    const int k = ks * 32 + (lane >> 4) * 8 + j, n = nt * 16 + (lane & 15);
    W1s1[i] = f2b(W1a[k * 128 + n]);
  }
  for (int i = t; i < 16384; i += stride) {
    const int j = i & 7, lane = (i >> 3) & 63, fb = i >> 9;
    const int ks = fb >> 3, nt = fb & 7;
    const int k = ks * 32 + (lane >> 4) * 8 + j, n = nt * 16 + (lane & 15);
    W1s2[i] = f2b(W1b[k * 128 + n]);
  }
  for (int i = t; i < 16384; i += stride) {
    const int n = i >> 7, k = i & 127;
    W2aT[i] = f2b(W2a[k * 128 + n]);
    W2bT[i] = f2b(W2b[k * 128 + n]);
  }
}

// ---- counting sort of edges by dst (grouping only; in-group order arbitrary) ----
__global__ void hist_dst(const int* __restrict__ dst, unsigned* __restrict__ cnt) {
  int i = blockIdx.x * blockDim.x + threadIdx.x;
  const int stride = gridDim.x * blockDim.x;
  for (; i < N_EDGES; i += stride) atomicAdd(&cnt[dst[i]], 1u);
}

// single-block in-place exclusive scan of cnt[N_NODES]
__global__ __launch_bounds__(1024) void scan_cnt(unsigned* __restrict__ cnt) {
  __shared__ unsigned wsum[16];
  __shared__ unsigned carry_s;
  const int tid = threadIdx.x;
  const int lane = tid & 63, wv = tid >> 6;
  if (tid == 0) carry_s = 0u;
  __syncthreads();
  for (int base = 0; base < N_NODES; base += 1024) {
    const int i = base + tid;
    const unsigned v = (i < N_NODES) ? cnt[i] : 0u;
    // wave-level inclusive scan (no barriers)
    unsigned s = v;
#pragma unroll
    for (int off = 1; off < 64; off <<= 1) {
      unsigned t = __shfl_up(s, off);
      if (lane >= off) s += t;
    }
    if (lane == 63) wsum[wv] = s;
    __syncthreads();
    if (wv == 0 && lane < 16) {
      unsigned w = wsum[lane];
      unsigned sw = w;
#pragma unroll
      for (int off = 1; off < 16; off <<= 1) {
        unsigned t = __shfl_up(sw, off);
        if (lane >= off) sw += t;
      }
      wsum[lane] = sw - w;  // exclusive wave offset
    }
    __syncthreads();
    const unsigned excl = s - v + wsum[wv] + carry_s;
    if (i < N_NODES) cnt[i] = excl;
    __syncthreads();
    if (tid == 1023) carry_s = excl + v;  // chunk total carried forward
    __syncthreads();
  }
}

__global__ void scatter_idx(const int* __restrict__ dst, unsigned* __restrict__ cnt,
                            unsigned* __restrict__ perm) {
  int i = blockIdx.x * blockDim.x + threadIdx.x;
  const int stride = gridDim.x * blockDim.x;
  for (; i < N_EDGES; i += stride) {
    const unsigned pos = atomicAdd(&cnt[dst[i]], 1u);
    perm[pos] = (unsigned)i;
  }
}

// ---- edge MLP over dst-sorted edges: 1 wave = 32 edges, run-aggregated scatter ----
__global__ __launch_bounds__(64, 4) void edge_mlp(
    const float* __restrict__ nf, const float* __restrict__ ef,
    const int* __restrict__ src, const int* __restrict__ dst,
    const unsigned* __restrict__ perm,
    const float* __restrict__ b1a, const float* __restrict__ b1b,
    const ushort_t* __restrict__ W1s1, const ushort_t* __restrict__ W1s2,
    float* __restrict__ agg) {
  // union: first 8704B double as Ys (bf16 GEMM1->GEMM2 staging); whole buffer is
  // Ms (f32 32x132 message tile) after GEMM2. 1 wave/block -> no barriers.
  __shared__ __align__(16) char smem[32 * MS_STRIDE * 4];  // 16896B
  ushort_t* Ys = (ushort_t*)smem;
  float* Ms = (float*)smem;

  const int lane = threadIdx.x;
  const int l16 = lane & 15;
  const int quad = lane >> 4;
  const int tb = blockIdx.x * 32;

  // dst of each sorted slot (lane r holds dst of row r, r<32); issued early
  int dlane = 0;
  if (lane < 32) dlane = dst[perm[tb + lane]];

  const int e0 = (int)perm[tb + l16];
  const int e1 = (int)perm[tb + 16 + l16];
  const int s0 = src[e0];
  const int s1 = src[e1];

  // GEMM1: acc[mt][nt] over K=256 (ks 0..3 = nf[src], 4..7 = ef[edge])
  floatx4 acc[2][8];
#pragma unroll
  for (int nt = 0; nt < 8; ++nt) {
    const float bz = b1a[nt * 16 + l16];
    acc[0][nt] = (floatx4){bz, bz, bz, bz};
    acc[1][nt] = acc[0][nt];
  }
#pragma unroll
  for (int ks = 0; ks < 8; ++ks) {
    short8 a0, a1;
    if (ks < 4) {
      const float4* p0 = (const float4*)nf + (long)s0 * 32 + ks * 8 + quad * 2;
      const float4* p1 = (const float4*)nf + (long)s1 * 32 + ks * 8 + quad * 2;
      a0 = mk_frag(p0[0], p0[1]);
      a1 = mk_frag(p1[0], p1[1]);
    } else {
      const float4* p0 = (const float4*)ef + (long)e0 * 32 + (ks - 4) * 8 + quad * 2;
      const float4* p1 = (const float4*)ef + (long)e1 * 32 + (ks - 4) * 8 + quad * 2;
      a0 = mk_frag(p0[0], p0[1]);
      a1 = mk_frag(p1[0], p1[1]);
    }
    short8 bfr[8];
#pragma unroll
    for (int nt = 0; nt < 8; ++nt)
      bfr[nt] = *(const short8*)(W1s1 + ((ks * 8 + nt) * 64 + lane) * 8);
#pragma unroll
    for (int nt = 0; nt < 8; ++nt) {
      acc[0][nt] = MFMA(a0, bfr[nt], acc[0][nt]);
      acc[1][nt] = MFMA(a1, bfr[nt], acc[1][nt]);
    }
  }

  // relu -> Ys (bf16, A-layout for GEMM2); within-wave: no barrier needed
#pragma unroll
  for (int mt = 0; mt < 2; ++mt)
#pragma unroll
    for (int nt = 0; nt < 8; ++nt)
#pragma unroll
      for (int r = 0; r < 4; ++r)
        Ys[(mt * 16 + quad * 4 + r) * YS_STRIDE + nt * 16 + l16] =
            f2b(fmaxf(acc[mt][nt][r], 0.f));

  // GEMM2: M = Y1 @ W1b + b1b
  floatx4 acc2[2][8];
#pragma unroll
  for (int nt = 0; nt < 8; ++nt) {
    const float bz = b1b[nt * 16 + l16];
    acc2[0][nt] = (floatx4){bz, bz, bz, bz};
    acc2[1][nt] = acc2[0][nt];
  }
#pragma unroll
  for (int ks = 0; ks < 4; ++ks) {
    const short8 a0 = *(const short8*)(&Ys[l16 * YS_STRIDE + ks * 32 + quad * 8]);
    const short8 a1 = *(const short8*)(&Ys[(16 + l16) * YS_STRIDE + ks * 32 + quad * 8]);
    short8 bfr[8];
#pragma unroll
    for (int nt = 0; nt < 8; ++nt)
      bfr[nt] = *(const short8*)(W1s2 + ((ks * 8 + nt) * 64 + lane) * 8);
#pragma unroll
    for (int nt = 0; nt < 8; ++nt) {
      acc2[0][nt] = MFMA(a0, bfr[nt], acc2[0][nt]);
      acc2[1][nt] = MFMA(a1, bfr[nt], acc2[1][nt]);
    }
  }

  // spill message tile to LDS as f32 (Ys is dead now; same buffer, program order kept)
#pragma unroll
  for (int mt = 0; mt < 2; ++mt)
#pragma unroll
    for (int nt = 0; nt < 8; ++nt)
#pragma unroll
      for (int r = 0; r < 4; ++r)
        Ms[(mt * 16 + quad * 4 + r) * MS_STRIDE + nt * 16 + l16] = acc2[mt][nt][r];

  // run-aggregated scatter: lane owns cols {lane, lane+64}; rows are dst-sorted,
  // so flush one atomic pair per distinct dst in the tile (~3 avg) instead of per row.
  float a0 = 0.f, a1 = 0.f;
  int cur = __shfl(dlane, 0);
  for (int r = 0; r < 32; ++r) {
    const int d = __shfl(dlane, r);  // wave-uniform
    if (d != cur) {
      unsafeAtomicAdd(&agg[(long)cur * 128 + lane], a0);
      unsafeAtomicAdd(&agg[(long)cur * 128 + 64 + lane], a1);
      a0 = 0.f; a1 = 0.f; cur = d;
    }
    a0 += Ms[r * MS_STRIDE + lane];
    a1 += Ms[r * MS_STRIDE + 64 + lane];
  }
  unsafeAtomicAdd(&agg[(long)cur * 128 + lane], a0);
  unsafeAtomicAdd(&agg[(long)cur * 128 + 64 + lane], a1);
}

// ---- node MLP: out = relu((agg + nf) @ W2a + b2a) @ W2b + b2b ----
__global__ __launch_bounds__(256) void node_mlp(
    const float* __restrict__ nf, const float* __restrict__ agg,
    const float* __restrict__ b2a, const float* __restrict__ b2b,
    const ushort_t* __restrict__ W2aT, const ushort_t* __restrict__ W2bT,
    float* __restrict__ out) {
  __shared__ __align__(16) ushort_t Xs[64 * YS_STRIDE];
  __shared__ __align__(16) ushort_t Ys2[64 * YS_STRIDE];

  const int tid = threadIdx.x;
  const int wave = tid >> 6;
  const int lane = tid & 63;
  const int l16 = lane & 15;
  const int quad = lane >> 4;
  const int nbase = wave * 32;
  const int rbase = blockIdx.x * 64;

  short8 bfrA[2][4], bfrB[2][4];
  float biasA[2], biasB[2];
#pragma unroll
  for (int t = 0; t < 2; ++t) {
    const int n = nbase + t * 16 + l16;
#pragma unroll
    for (int ks = 0; ks < 4; ++ks) {
      bfrA[t][ks] = *(const short8*)(W2aT + n * 128 + ks * 32 + quad * 8);
      bfrB[t][ks] = *(const short8*)(W2bT + n * 128 + ks * 32 + quad * 8);
    }
    biasA[t] = b2a[n];
    biasB[t] = b2b[n];
  }

#pragma unroll
  for (int i = 0; i < 8; ++i) {
    const int fidx = tid + 256 * i;
    const int r = fidx >> 5;
    const int c4 = fidx & 31;
    const long gr = min(rbase + r, N_NODES - 1);
    const float4 a = ((const float4*)agg)[gr * 32 + c4];
    const float4 n = ((const float4*)nf)[gr * 32 + c4];
    unsigned* p = (unsigned*)&Xs[r * YS_STRIDE + c4 * 4];
    p[0] = pk2(a.x + n.x, a.y + n.y);
    p[1] = pk2(a.z + n.z, a.w + n.w);
  }
  __syncthreads();

  floatx4 acc[4][2];
#pragma unroll
  for (int mt = 0; mt < 4; ++mt)
#pragma unroll
    for (int t = 0; t < 2; ++t)
      acc[mt][t] = (floatx4){biasA[t], biasA[t], biasA[t], biasA[t]};
#pragma unroll
  for (int ks = 0; ks < 4; ++ks)
#pragma unroll
    for (int mt = 0; mt < 4; ++mt) {
      const short8 a = *(const short8*)(&Xs[(mt * 16 + l16) * YS_STRIDE + ks * 32 + quad * 8]);
      acc[mt][0] = MFMA(a, bfrA[0][ks], acc[mt][0]);
      acc[mt][1] = MFMA(a, bfrA[1][ks], acc[mt][1]);
    }
#pragma unroll
  for (int mt = 0; mt < 4; ++mt)
#pragma unroll
    for (int t = 0; t < 2; ++t)
#pragma unroll
      for (int r = 0; r < 4; ++r) {
        const int row = mt * 16 + quad * 4 + r;
        const int col = nbase + t * 16 + l16;
        Ys2[row * YS_STRIDE + col] = f2b(fmaxf(acc[mt][t][r], 0.f));
      }
  __syncthreads();

  floatx4 acc2[4][2];
#pragma unroll
  for (int mt = 0; mt < 4; ++mt)
#pragma unroll
    for (int t = 0; t < 2; ++t)
      acc2[mt][t] = (floatx4){biasB[t], biasB[t], biasB[t], biasB[t]};
#pragma unroll
  for (int ks = 0; ks < 4; ++ks)
#pragma unroll
    for (int mt = 0; mt < 4; ++mt) {
      const short8 a = *(const short8*)(&Ys2[(mt * 16 + l16) * YS_STRIDE + ks * 32 + quad * 8]);
      acc2[mt][0] = MFMA(a, bfrB[0][ks], acc2[mt][0]);
      acc2[mt][1] = MFMA(a, bfrB[1][ks], acc2[mt][1]);
    }
#pragma unroll
  for (int mt = 0; mt < 4; ++mt)
#pragma unroll
    for (int t = 0; t < 2; ++t)
#pragma unroll
      for (int r = 0; r < 4; ++r) {
        const int row = mt * 16 + quad * 4 + r;
        const int grow = rbase + row;
        if (grow < N_NODES) {
          const int col = nbase + t * 16 + l16;
          out[(long)grow * 128 + col] = acc2[mt][t][r];
        }
      }
}

extern "C" void kernel_launch(void* const* d_in, const int* in_sizes, int n_in,
                              void* d_out, int out_size, void* d_ws, size_t ws_size,
                              hipStream_t stream) {
  const float* nf = (const float*)d_in[0];
  const float* ef = (const float*)d_in[1];
  const int* src = (const int*)d_in[2];
  const int* dst = (const int*)d_in[3];
  const float* W1a = (const float*)d_in[4];
  const float* b1a = (const float*)d_in[5];
  const float* W1b = (const float*)d_in[6];
  const float* b1b = (const float*)d_in[7];
  const float* W2a = (const float*)d_in[8];
  const float* b2a = (const float*)d_in[9];
  const float* W2b = (const float*)d_in[10];
  const float* b2b = (const float*)d_in[11];
  float* out = (float*)d_out;

  // ws: agg fp32 [50000*128] @0 (25.6MB), wbuf bf16 weights @25600000 (163840B)
  char* ws = (char*)d_ws;
  float* agg = (float*)ws;
  ushort_t* wbuf = (ushort_t*)(ws + 25600000);
  const ushort_t* W1s1 = wbuf;
  const ushort_t* W1s2 = wbuf + 32768;
  const ushort_t* W2aT = wbuf + 49152;
  const ushort_t* W2bT = wbuf + 65536;

  // sort scratch lives in d_out (dead until node_mlp overwrites it):
  // cnt: [0, 50000) u32; perm: [65536, 865536) u32  (3.5MB << 25.6MB)
  unsigned* cnt = (unsigned*)out;
  unsigned* perm = (unsigned*)out + 65536;

  prep<<<1024, 256, 0, stream>>>(W1a, W1b, W2a, W2b, wbuf, (float4*)agg, cnt);
  hist_dst<<<1024, 256, 0, stream>>>(dst, cnt);
  scan_cnt<<<1, 1024, 0, stream>>>(cnt);
  scatter_idx<<<1024, 256, 0, stream>>>(dst, cnt, perm);
  edge_mlp<<<EDGE_BLOCKS, 64, 0, stream>>>(nf, ef, src, dst, perm, b1a, b1b, W1s1, W1s2, agg);
  node_mlp<<<NODE_TILES, 256, 0, stream>>>(nf, agg, b2a, b2b, W2aT, W2bT, out);
}

// Round 3
// 858.192 us; speedup vs baseline: 1.1662x; 1.0881x over previous
//
#include <hip/hip_runtime.h>
#include <hip/hip_bf16.h>

typedef __attribute__((ext_vector_type(8))) short short8;
typedef __attribute__((ext_vector_type(4))) float floatx4;
typedef unsigned short ushort_t;

#define MFMA(a, b, c) __builtin_amdgcn_mfma_f32_16x16x32_bf16((a), (b), (c), 0, 0, 0)

constexpr int N_NODES = 50000;
constexpr int N_EDGES = 800000;
constexpr int EDGE_BLOCKS = N_EDGES / 32;        // 25000 (exact)
constexpr int NODE_TILES = (N_NODES + 63) / 64;  // 782
constexpr int SCAN_BLOCKS = (N_NODES + 1023) / 1024;  // 49
constexpr int YS_STRIDE = 136;                   // u16; 272B row, 16B-aligned, ~2-way bank alias (free)

__device__ __forceinline__ unsigned short f2b(float x) {
  union { float f; unsigned u; } c; c.f = x;
  unsigned r = c.u + 0x7FFFu + ((c.u >> 16) & 1u);
  return (unsigned short)(r >> 16);
}

__device__ __forceinline__ unsigned pk2(float x, float y) {
  // packed RNE fp32->bf16 (v_cvt_pk_bf16_f32 on gfx950)
  __hip_bfloat162 h = __float22bfloat162_rn(float2{x, y});
  unsigned u; __builtin_memcpy(&u, &h, 4);
  return u;
}

__device__ __forceinline__ short8 mk_frag(const float4 a, const float4 b) {
  union { short8 s; unsigned u[4]; } r;
  r.u[0] = pk2(a.x, a.y); r.u[1] = pk2(a.z, a.w);
  r.u[2] = pk2(b.x, b.y); r.u[3] = pk2(b.z, b.w);
  return r.s;
}

// ---- prep: zero agg + zero dst-histogram + build weights ----
__global__ void prep(const float* __restrict__ W1a, const float* __restrict__ W1b,
                     const float* __restrict__ W2a, const float* __restrict__ W2b,
                     ushort_t* __restrict__ wbuf, float4* __restrict__ agg4,
                     unsigned* __restrict__ cnt) {
  const int t = blockIdx.x * blockDim.x + threadIdx.x;
  const int stride = gridDim.x * blockDim.x;
  const float4 z = {0.f, 0.f, 0.f, 0.f};
  for (int i = t; i < N_NODES * 32; i += stride) agg4[i] = z;
  for (int i = t; i < N_NODES; i += stride) cnt[i] = 0u;

  ushort_t* W1s1 = wbuf;           // 32768: GEMM1 frags (ks=0..7, nt=0..7)
  ushort_t* W1s2 = wbuf + 32768;   // 16384: GEMM2 frags (ks=0..3, nt=0..7)
  ushort_t* W2aT = wbuf + 49152;   // 16384
  ushort_t* W2bT = wbuf + 65536;   // 16384

  for (int i = t; i < 32768; i += stride) {
    const int j = i & 7, lane = (i >> 3) & 63, fb = i >> 9;
    const int ks = fb >> 3, nt = fb & 7;
    const int k = ks * 32 + (lane >> 4) * 8 + j, n = nt * 16 + (lane & 15);
    W1s1[i] = f2b(W1a[k * 128 + n]);
  }
  for (int i = t; i < 16384; i += stride) {
    const int j = i & 7, lane = (i >> 3) & 63, fb = i >> 9;
    const int ks = fb >> 3, nt = fb & 7;
    const int k = ks * 32 + (lane >> 4) * 8 + j, n = nt * 16 + (lane & 15);
    W1s2[i] = f2b(W1b[k * 128 + n]);
  }
  for (int i = t; i < 16384; i += stride) {
    const int n = i >> 7, k = i & 127;
    W2aT[i] = f2b(W2a[k * 128 + n]);
    W2bT[i] = f2b(W2b[k * 128 + n]);
  }
}

// ---- counting sort of edges by dst (grouping only; in-group order arbitrary) ----
__global__ void hist_dst(const int* __restrict__ dst, unsigned* __restrict__ cnt) {
  int i = blockIdx.x * blockDim.x + threadIdx.x;
  const int stride = gridDim.x * blockDim.x;
  for (; i < N_EDGES; i += stride) atomicAdd(&cnt[dst[i]], 1u);
}

// hierarchical exclusive scan of cnt[N_NODES]: 49-block scan + 1-wave bsum scan + add-back
__global__ __launch_bounds__(1024) void scan1(unsigned* __restrict__ cnt,
                                              unsigned* __restrict__ bsum) {
  __shared__ unsigned wsum[16];
  const int tid = threadIdx.x, lane = tid & 63, wv = tid >> 6;
  const int i = blockIdx.x * 1024 + tid;
  const unsigned v = (i < N_NODES) ? cnt[i] : 0u;
  unsigned s = v;
#pragma unroll
  for (int off = 1; off < 64; off <<= 1) {
    unsigned t = __shfl_up(s, off);
    if (lane >= off) s += t;
  }
  if (lane == 63) wsum[wv] = s;
  __syncthreads();
  if (wv == 0 && lane < 16) {
    unsigned w = wsum[lane], sw = w;
#pragma unroll
    for (int off = 1; off < 16; off <<= 1) {
      unsigned t = __shfl_up(sw, off);
      if (lane >= off) sw += t;
    }
    wsum[lane] = sw - w;  // exclusive wave offset
    if (lane == 15) bsum[blockIdx.x] = sw;  // block total
  }
  __syncthreads();
  if (i < N_NODES) cnt[i] = s - v + wsum[wv];
}

__global__ void scan2(unsigned* __restrict__ bsum) {
  const int lane = threadIdx.x;  // 64 threads, 1 block
  const unsigned v = (lane < SCAN_BLOCKS) ? bsum[lane] : 0u;
  unsigned s = v;
#pragma unroll
  for (int off = 1; off < 64; off <<= 1) {
    unsigned t = __shfl_up(s, off);
    if (lane >= off) s += t;
  }
  if (lane < SCAN_BLOCKS) bsum[lane] = s - v;  // exclusive
}

__global__ __launch_bounds__(1024) void scan3(unsigned* __restrict__ cnt,
                                              const unsigned* __restrict__ bsum) {
  const int i = blockIdx.x * 1024 + threadIdx.x;
  if (i < N_NODES) cnt[i] += bsum[blockIdx.x];
}

__global__ void scatter_idx(const int* __restrict__ dst, unsigned* __restrict__ cnt,
                            unsigned* __restrict__ perm) {
  int i = blockIdx.x * blockDim.x + threadIdx.x;
  const int stride = gridDim.x * blockDim.x;
  for (; i < N_EDGES; i += stride) {
    const unsigned pos = atomicAdd(&cnt[dst[i]], 1u);
    perm[pos] = (unsigned)i;
  }
}

// ---- edge MLP over dst-sorted edges: 1 wave = 32 edges ----
// Run-aggregation fully in registers: ballot run boundaries, masked sums over acc2,
// quad-fold via shfl_xor(16/32), 2 column atomics per lane per run. No Ms LDS tile.
__global__ __launch_bounds__(64, 4) void edge_mlp(
    const float* __restrict__ nf, const float* __restrict__ ef,
    const int* __restrict__ src, const int* __restrict__ dst,
    const unsigned* __restrict__ perm,
    const float* __restrict__ b1a, const float* __restrict__ b1b,
    const ushort_t* __restrict__ W1s1, const ushort_t* __restrict__ W1s2,
    float* __restrict__ agg) {
  __shared__ __align__(16) ushort_t Ys[32 * YS_STRIDE];  // 8704B, wave-private

  const int lane = threadIdx.x;
  const int l16 = lane & 15;
  const int quad = lane >> 4;
  const int tb = blockIdx.x * 32;

  // permuted edge id + dst per row (lane r holds row r, r<32)
  int plane = 0;
  if (lane < 32) plane = (int)perm[tb + lane];
  int dlane = 0;
  if (lane < 32) dlane = dst[plane];

  const int e0 = __shfl(plane, l16);
  const int e1 = __shfl(plane, 16 + l16);
  const int s0 = src[e0];
  const int s1 = src[e1];

  // GEMM1: acc[mt][nt] over K=256 (ks 0..3 = nf[src], 4..7 = ef[edge])
  floatx4 acc[2][8];
#pragma unroll
  for (int nt = 0; nt < 8; ++nt) {
    const float bz = b1a[nt * 16 + l16];
    acc[0][nt] = (floatx4){bz, bz, bz, bz};
    acc[1][nt] = acc[0][nt];
  }
#pragma unroll
  for (int ks = 0; ks < 8; ++ks) {
    short8 a0, a1;
    if (ks < 4) {
      const float4* p0 = (const float4*)nf + (long)s0 * 32 + ks * 8 + quad * 2;
      const float4* p1 = (const float4*)nf + (long)s1 * 32 + ks * 8 + quad * 2;
      a0 = mk_frag(p0[0], p0[1]);
      a1 = mk_frag(p1[0], p1[1]);
    } else {
      const float4* p0 = (const float4*)ef + (long)e0 * 32 + (ks - 4) * 8 + quad * 2;
      const float4* p1 = (const float4*)ef + (long)e1 * 32 + (ks - 4) * 8 + quad * 2;
      a0 = mk_frag(p0[0], p0[1]);
      a1 = mk_frag(p1[0], p1[1]);
    }
    short8 bfr[8];
#pragma unroll
    for (int nt = 0; nt < 8; ++nt)
      bfr[nt] = *(const short8*)(W1s1 + ((ks * 8 + nt) * 64 + lane) * 8);
#pragma unroll
    for (int nt = 0; nt < 8; ++nt) {
      acc[0][nt] = MFMA(a0, bfr[nt], acc[0][nt]);
      acc[1][nt] = MFMA(a1, bfr[nt], acc[1][nt]);
    }
  }

  // relu -> Ys (bf16, A-layout for GEMM2); within-wave: no barrier needed
#pragma unroll
  for (int mt = 0; mt < 2; ++mt)
#pragma unroll
    for (int nt = 0; nt < 8; ++nt)
#pragma unroll
      for (int r = 0; r < 4; ++r)
        Ys[(mt * 16 + quad * 4 + r) * YS_STRIDE + nt * 16 + l16] =
            f2b(fmaxf(acc[mt][nt][r], 0.f));

  // GEMM2: M = Y1 @ W1b + b1b  (bias per-edge, so run-sums carry it correctly)
  floatx4 acc2[2][8];
#pragma unroll
  for (int nt = 0; nt < 8; ++nt) {
    const float bz = b1b[nt * 16 + l16];
    acc2[0][nt] = (floatx4){bz, bz, bz, bz};
    acc2[1][nt] = acc2[0][nt];
  }
#pragma unroll
  for (int ks = 0; ks < 4; ++ks) {
    const short8 a0 = *(const short8*)(&Ys[l16 * YS_STRIDE + ks * 32 + quad * 8]);
    const short8 a1 = *(const short8*)(&Ys[(16 + l16) * YS_STRIDE + ks * 32 + quad * 8]);
    short8 bfr[8];
#pragma unroll
    for (int nt = 0; nt < 8; ++nt)
      bfr[nt] = *(const short8*)(W1s2 + ((ks * 8 + nt) * 64 + lane) * 8);
#pragma unroll
    for (int nt = 0; nt < 8; ++nt) {
      acc2[0][nt] = MFMA(a0, bfr[nt], acc2[0][nt]);
      acc2[1][nt] = MFMA(a1, bfr[nt], acc2[1][nt]);
    }
  }

  // ---- in-register run-aggregated scatter ----
  // Run boundaries: rows are dst-sorted; flag where dlane changes.
  const int dprev = __shfl_up(dlane, 1);
  const bool flag = (lane == 0) || (dlane != dprev);
  const unsigned long long m = __ballot(flag) & 0xFFFFFFFFull;  // bit r = run starts at row r

  int lo = 0;
  while (true) {
    const unsigned long long rest = m >> (lo + 1);
    const int hi = rest ? (lo + 1 + __builtin_ctzll(rest)) : 32;
    const int d = __shfl(dlane, lo);  // wave-uniform dst of this run

    // masked per-column partial sums over this lane's rows in [lo,hi)
    float s[8];
#pragma unroll
    for (int nt = 0; nt < 8; ++nt) s[nt] = 0.f;
#pragma unroll
    for (int mt = 0; mt < 2; ++mt)
#pragma unroll
      for (int r = 0; r < 4; ++r) {
        const int row = mt * 16 + quad * 4 + r;
        const bool in = (row >= lo) && (row < hi);
#pragma unroll
        for (int nt = 0; nt < 8; ++nt)
          s[nt] += in ? acc2[mt][nt][r] : 0.f;
      }
    // fold quad dimension: after xor16+xor32 every lane holds the full column sum
#pragma unroll
    for (int nt = 0; nt < 8; ++nt) {
      s[nt] += __shfl_xor(s[nt], 16);
      s[nt] += __shfl_xor(s[nt], 32);
    }
    // quad q flushes columns nt=2q, 2q+1 (static selects; no runtime array index)
    const float v0 = quad == 0 ? s[0] : quad == 1 ? s[2] : quad == 2 ? s[4] : s[6];
    const float v1 = quad == 0 ? s[1] : quad == 1 ? s[3] : quad == 2 ? s[5] : s[7];
    unsafeAtomicAdd(&agg[(long)d * 128 + quad * 32 + l16], v0);
    unsafeAtomicAdd(&agg[(long)d * 128 + quad * 32 + 16 + l16], v1);

    if (hi >= 32) break;
    lo = hi;
  }
}

// ---- node MLP: out = relu((agg + nf) @ W2a + b2a) @ W2b + b2b ----
__global__ __launch_bounds__(256) void node_mlp(
    const float* __restrict__ nf, const float* __restrict__ agg,
    const float* __restrict__ b2a, const float* __restrict__ b2b,
    const ushort_t* __restrict__ W2aT, const ushort_t* __restrict__ W2bT,
    float* __restrict__ out) {
  __shared__ __align__(16) ushort_t Xs[64 * YS_STRIDE];
  __shared__ __align__(16) ushort_t Ys2[64 * YS_STRIDE];

  const int tid = threadIdx.x;
  const int wave = tid >> 6;
  const int lane = tid & 63;
  const int l16 = lane & 15;
  const int quad = lane >> 4;
  const int nbase = wave * 32;
  const int rbase = blockIdx.x * 64;

  short8 bfrA[2][4], bfrB[2][4];
  float biasA[2], biasB[2];
#pragma unroll
  for (int t = 0; t < 2; ++t) {
    const int n = nbase + t * 16 + l16;
#pragma unroll
    for (int ks = 0; ks < 4; ++ks) {
      bfrA[t][ks] = *(const short8*)(W2aT + n * 128 + ks * 32 + quad * 8);
      bfrB[t][ks] = *(const short8*)(W2bT + n * 128 + ks * 32 + quad * 8);
    }
    biasA[t] = b2a[n];
    biasB[t] = b2b[n];
  }

#pragma unroll
  for (int i = 0; i < 8; ++i) {
    const int fidx = tid + 256 * i;
    const int r = fidx >> 5;
    const int c4 = fidx & 31;
    const long gr = min(rbase + r, N_NODES - 1);
    const float4 a = ((const float4*)agg)[gr * 32 + c4];
    const float4 n = ((const float4*)nf)[gr * 32 + c4];
    unsigned* p = (unsigned*)&Xs[r * YS_STRIDE + c4 * 4];
    p[0] = pk2(a.x + n.x, a.y + n.y);
    p[1] = pk2(a.z + n.z, a.w + n.w);
  }
  __syncthreads();

  floatx4 acc[4][2];
#pragma unroll
  for (int mt = 0; mt < 4; ++mt)
#pragma unroll
    for (int t = 0; t < 2; ++t)
      acc[mt][t] = (floatx4){biasA[t], biasA[t], biasA[t], biasA[t]};
#pragma unroll
  for (int ks = 0; ks < 4; ++ks)
#pragma unroll
    for (int mt = 0; mt < 4; ++mt) {
      const short8 a = *(const short8*)(&Xs[(mt * 16 + l16) * YS_STRIDE + ks * 32 + quad * 8]);
      acc[mt][0] = MFMA(a, bfrA[0][ks], acc[mt][0]);
      acc[mt][1] = MFMA(a, bfrA[1][ks], acc[mt][1]);
    }
#pragma unroll
  for (int mt = 0; mt < 4; ++mt)
#pragma unroll
    for (int t = 0; t < 2; ++t)
#pragma unroll
      for (int r = 0; r < 4; ++r) {
        const int row = mt * 16 + quad * 4 + r;
        const int col = nbase + t * 16 + l16;
        Ys2[row * YS_STRIDE + col] = f2b(fmaxf(acc[mt][t][r], 0.f));
      }
  __syncthreads();

  floatx4 acc2[4][2];
#pragma unroll
  for (int mt = 0; mt < 4; ++mt)
#pragma unroll
    for (int t = 0; t < 2; ++t)
      acc2[mt][t] = (floatx4){biasB[t], biasB[t], biasB[t], biasB[t]};
#pragma unroll
  for (int ks = 0; ks < 4; ++ks)
#pragma unroll
    for (int mt = 0; mt < 4; ++mt) {
      const short8 a = *(const short8*)(&Ys2[(mt * 16 + l16) * YS_STRIDE + ks * 32 + quad * 8]);
      acc2[mt][0] = MFMA(a, bfrB[0][ks], acc2[mt][0]);
      acc2[mt][1] = MFMA(a, bfrB[1][ks], acc2[mt][1]);
    }
#pragma unroll
  for (int mt = 0; mt < 4; ++mt)
#pragma unroll
    for (int t = 0; t < 2; ++t)
#pragma unroll
      for (int r = 0; r < 4; ++r) {
        const int row = mt * 16 + quad * 4 + r;
        const int grow = rbase + row;
        if (grow < N_NODES) {
          const int col = nbase + t * 16 + l16;
          out[(long)grow * 128 + col] = acc2[mt][t][r];
        }
      }
}

extern "C" void kernel_launch(void* const* d_in, const int* in_sizes, int n_in,
                              void* d_out, int out_size, void* d_ws, size_t ws_size,
                              hipStream_t stream) {
  const float* nf = (const float*)d_in[0];
  const float* ef = (const float*)d_in[1];
  const int* src = (const int*)d_in[2];
  const int* dst = (const int*)d_in[3];
  const float* W1a = (const float*)d_in[4];
  const float* b1a = (const float*)d_in[5];
  const float* W1b = (const float*)d_in[6];
  const float* b1b = (const float*)d_in[7];
  const float* W2a = (const float*)d_in[8];
  const float* b2a = (const float*)d_in[9];
  const float* W2b = (const float*)d_in[10];
  const float* b2b = (const float*)d_in[11];
  float* out = (float*)d_out;

  // ws: agg fp32 [50000*128] @0 (25.6MB), wbuf bf16 weights @25600000 (163840B)
  char* ws = (char*)d_ws;
  float* agg = (float*)ws;
  ushort_t* wbuf = (ushort_t*)(ws + 25600000);
  const ushort_t* W1s1 = wbuf;
  const ushort_t* W1s2 = wbuf + 32768;
  const ushort_t* W2aT = wbuf + 49152;
  const ushort_t* W2bT = wbuf + 65536;

  // sort scratch lives in d_out (dead until node_mlp overwrites it):
  // cnt: [0, 50000) u32; perm: [65536, 865536) u32; bsum: [865536, 865600) u32
  unsigned* cnt = (unsigned*)out;
  unsigned* perm = (unsigned*)out + 65536;
  unsigned* bsum = (unsigned*)out + 65536 + 800000;

  prep<<<1024, 256, 0, stream>>>(W1a, W1b, W2a, W2b, wbuf, (float4*)agg, cnt);
  hist_dst<<<1024, 256, 0, stream>>>(dst, cnt);
  scan1<<<SCAN_BLOCKS, 1024, 0, stream>>>(cnt, bsum);
  scan2<<<1, 64, 0, stream>>>(bsum);
  scan3<<<SCAN_BLOCKS, 1024, 0, stream>>>(cnt, bsum);
  scatter_idx<<<1024, 256, 0, stream>>>(dst, cnt, perm);
  edge_mlp<<<EDGE_BLOCKS, 64, 0, stream>>>(nf, ef, src, dst, perm, b1a, b1b, W1s1, W1s2, agg);
  node_mlp<<<NODE_TILES, 256, 0, stream>>>(nf, agg, b2a, b2b, W2aT, W2bT, out);
}